// Round 3
// baseline (102.215 us; speedup 1.0000x reference)
//
#include <hip/hip_runtime.h>
#include <hip/hip_bf16.h>

// ---------------- problem constants ----------------
#define Bn    8
#define MO    12
#define Dd    512
#define NOBJ  37
#define NACT  6
#define NTRS  3
#define EMB   128
#define NAA   100
#define NCLS  300
#define Kk    72            // MO*NACT
#define Pp    5112          // Kk*(Kk-1)
#define HALF  768           // Dd + 2*EMB
#define FD    1536          // 2*HALF

// output layout (concatenated return order)
#define OUT_FINAL 0
#define OUT_PLOG  (Bn*NCLS)                       // 2400
#define OUT_TTGT  (OUT_PLOG + Bn*Pp*NTRS)         // 125088
#define OUT_ACT   (OUT_TTGT + Bn*Pp*NTRS)         // 247776
#define OUT_OBJ   (OUT_ACT + Bn*Kk)               // 248352

// ---------------- workspace layout (4-byte units) ----------------
#define WS_LINP 0                                 // [B,MO,6] f32 (th = t*2+h)
#define WS_EO   (WS_LINP + Bn*MO*6)               // [NOBJ,6]
#define WS_EA   (WS_EO + NOBJ*6)                  // [NACT,6]
#define WS_INV  (WS_EA + NACT*6)                  // [3]
#define WS_NE   (WS_INV + 6)                      // [B,NCLS]
#define WS_SEG  (WS_NE + Bn*NCLS)                 // [B,NCLS] u32
#define WS_PRED (WS_SEG + Bn*NCLS)                // [B,MO] i32
#define WS_SEL  (WS_PRED + Bn*MO)                 // [B,K] i32
#define WS_AAI  (WS_SEL + Bn*Kk)                  // [B,K] i32

// monotonic float <-> uint; 0u is below any finite mapped value = "empty"
__device__ __forceinline__ unsigned fmap(float f) {
  unsigned u = __float_as_uint(f);
  return (u & 0x80000000u) ? ~u : (u | 0x80000000u);
}
__device__ __forceinline__ float funmap(unsigned u) {
  return __uint_as_float((u & 0x80000000u) ? (u & 0x7fffffffu) : ~u);
}

__device__ __forceinline__ float wreduce(float v) {
#pragma unroll
  for (int off = 32; off > 0; off >>= 1) v += __shfl_xor(v, off, 64);
  return v;
}

// 512-dot with the x-operand preloaded (lane holds float4 #lane, #(lane+64))
__device__ __forceinline__ float dotW(const float* __restrict__ wrow,
                                      float4 x0, float4 x1, int lane) {
  const float4* w4 = (const float4*)wrow;
  float4 w0 = w4[lane], w1 = w4[lane + 64];
  float s0 = fmaf(w0.x, x0.x, fmaf(w0.y, x0.y, fmaf(w0.z, x0.z, w0.w * x0.w)));
  float s1 = fmaf(w1.x, x1.x, fmaf(w1.y, x1.y, fmaf(w1.z, x1.z, w1.w * x1.w)));
  return wreduce(s0 + s1);
}

__device__ __forceinline__ float dot512_wave(const float* __restrict__ a,
                                             const float* __restrict__ b, int lane) {
  const float4* b4 = (const float4*)b;
  return dotW(a, b4[lane], b4[lane + 64], lane);
}

// 128-dot, lane holds one float2
__device__ __forceinline__ float dot128_wave(const float* __restrict__ a,
                                             const float* __restrict__ b, int lane) {
  const float2* a2 = (const float2*)a;
  const float2* b2 = (const float2*)b;
  float2 x = a2[lane], y = b2[lane];
  return wreduce(fmaf(x.x, y.x, x.y * y.y));
}

// ---------------- K1: ALL independent work (single dependency-free phase) ----
#define W_TOBJ  (Bn*MO)                   // 96 waves: 37 obj dots + argmax each
#define W_TACT  (W_TOBJ + Bn*MO)          // 192: 6 act dots + selection each
#define W_TLINP (W_TACT + Bn*MO*6)        // 768: one 512-dot each
#define W_TEO   (W_TLINP + NOBJ*6)        // 990: obj_emb x W_tr halves
#define W_TEA   (W_TEO + NACT*6)          // 1026
#define W_TINV  (W_TEA + NTRS)            // 1029: all-(-1) row constants
#define W_TNE   (W_TINV + Bn*NCLS)        // 3429: pool-inline + W_ne dot
#define W_TOT   (W_TNE + 38)              // 3467 (ceil(2400/64)=38 zero waves)

__global__ __launch_bounds__(256) void k1(
    const float* __restrict__ inp, const float* __restrict__ objmask,
    const float* __restrict__ W_obj, const float* __restrict__ b_obj,
    const float* __restrict__ W_act, const float* __restrict__ b_act,
    const float* __restrict__ W_tr, const float* __restrict__ b_tr,
    const float* __restrict__ W_ne, const float* __restrict__ b_ne,
    const float* __restrict__ obj_emb, const float* __restrict__ act_emb,
    const int* __restrict__ AA,
    float* __restrict__ out, float* __restrict__ ws)
{
  int gt = blockIdx.x * 256 + threadIdx.x;
  int w = gt >> 6, lane = gt & 63;

  if (w < W_TOBJ) {
    // ---- one wave per (b,o): 37 obj dots, first-max argmax, write obj_out
    int b = w / MO, o = w % MO;
    const float4* x4 = (const float4*)(inp + (b*MO + o)*Dd);
    float4 x0 = x4[lane], x1 = x4[lane + 64];
    float myval = 0.f, best = 0.f;
    int bi = 0;
    for (int c = 0; c < NOBJ; ++c) {
      float s = dotW(W_obj + c*Dd, x0, x1, lane) + b_obj[c];
      if (lane == c) myval = s;
      if (c == 0 || s > best) { best = s; bi = c; }   // strict > keeps FIRST max
    }
    if (lane < NOBJ) out[OUT_OBJ + (b*MO + o)*NOBJ + lane] = myval;
    if (lane == 0) ((int*)ws)[WS_PRED + b*MO + o] = bi;
  } else if (w < W_TACT) {
    // ---- one wave per (b,o): 6 act dots + selection flags
    int r = w - W_TOBJ, b = r / MO, o = r % MO;
    const float4* x4 = (const float4*)(inp + (b*MO + o)*Dd);
    float4 x0 = x4[lane], x1 = x4[lane + 64];
    float myv = 0.f;
    for (int a = 0; a < NACT; ++a) {
      float s = dotW(W_act + a*Dd, x0, x1, lane) + b_act[a];
      if (lane == a) myv = s;
    }
    if (lane < NACT) {
      int k = o*NACT + lane;
      out[OUT_ACT + b*Kk + k] = myv;
      int aa = AA[b*Kk + k];
      // sigmoid(x)>0.5 <=> x>0 ; pred_act==1.0 also needs mask==1.0
      int sel = (myv > 0.f) && (objmask[b*MO + o] == 1.0f) && (aa != -1);
      ((int*)ws)[WS_SEL + b*Kk + k] = sel;
      ((int*)ws)[WS_AAI + b*Kk + k] = sel ? aa : -1;
    }
  } else if (w < W_TLINP) {
    int r = w - W_TACT, b = r / (MO*6), r2 = r % (MO*6), o = r2 / 6, th = r2 % 6;
    int t = th >> 1, h = th & 1;
    float v = dot512_wave(W_tr + t*FD + h*HALF, inp + (b*MO + o)*Dd, lane);
    if (!lane) ws[WS_LINP + (b*MO + o)*6 + th] = v;
  } else if (w < W_TEO) {
    int r = w - W_TLINP, oc = r / 6, th = r % 6, t = th >> 1, h = th & 1;
    float v = dot128_wave(W_tr + t*FD + h*HALF + Dd, obj_emb + oc*EMB, lane);
    if (!lane) ws[WS_EO + oc*6 + th] = v;
  } else if (w < W_TEA) {
    int r = w - W_TEO, a = r / 6, th = r % 6, t = th >> 1, h = th & 1;
    float v = dot128_wave(W_tr + t*FD + h*HALF + Dd + EMB, act_emb + a*EMB, lane);
    if (!lane) ws[WS_EA + a*6 + th] = v;
  } else if (w < W_TINV) {
    int t = w - W_TEA;
    const float4* w4 = (const float4*)(W_tr + t*FD);
    float s = 0.f;
#pragma unroll
    for (int i = 0; i < 6; ++i) { float4 x = w4[lane + 64*i]; s += x.x + x.y + x.z + x.w; }
    s = wreduce(s);
    if (!lane) ws[WS_INV + t] = b_tr[t] - s;          // all-(-1) pair-row logit
  } else if (w < W_TNE) {
    // ---- one wave per (b,c): masked-mean pool inline, then W_ne dot
    int r = w - W_TINV, b = r / NCLS, c = r % NCLS;
    const float4* i4 = (const float4*)inp;
    float msum = 0.f;
    float4 p0 = make_float4(0.f, 0.f, 0.f, 0.f), p1 = p0;
#pragma unroll
    for (int o = 0; o < MO; ++o) {
      float m = objmask[b*MO + o];
      msum += m;
      float4 v0 = i4[(b*MO + o)*128 + lane];
      float4 v1 = i4[(b*MO + o)*128 + lane + 64];
      p0.x = fmaf(m, v0.x, p0.x); p0.y = fmaf(m, v0.y, p0.y);
      p0.z = fmaf(m, v0.z, p0.z); p0.w = fmaf(m, v0.w, p0.w);
      p1.x = fmaf(m, v1.x, p1.x); p1.y = fmaf(m, v1.y, p1.y);
      p1.z = fmaf(m, v1.z, p1.z); p1.w = fmaf(m, v1.w, p1.w);
    }
    float v = dotW(W_ne + c*Dd, p0, p1, lane) / msum + b_ne[c];
    if (!lane) ws[WS_NE + b*NCLS + c] = v;
  } else if (w < W_TOT) {
    int idx = (w - W_TNE)*64 + lane;
    if (idx < Bn*NCLS) ((unsigned*)ws)[WS_SEG + idx] = 0u;
  }
}

// ---------------- K2: pair loop (closed-form packed destination) ----------------
#define NSLICE 20

__global__ __launch_bounds__(256) void k2(
    const float* __restrict__ TRt, const float* __restrict__ b_tr,
    const int* __restrict__ aalut,
    float* __restrict__ out, float* __restrict__ ws)
{
  __shared__ float s_L[Kk*6];              // [k][t*2+h], h==0 half includes b_tr
  __shared__ float s_inv[NTRS];
  __shared__ int s_sel[Kk], s_aa[Kk], s_C[Kk], s_T;

  int b = blockIdx.x / NSLICE, slice = blockIdx.x % NSLICE;
  int tid = threadIdx.x;

  if (tid < Kk) {
    s_sel[tid] = ((const int*)ws)[WS_SEL + b*Kk + tid];
    s_aa[tid]  = ((const int*)ws)[WS_AAI + b*Kk + tid];
  } else if (tid < Kk + NTRS) {
    s_inv[tid - Kk] = ws[WS_INV + (tid - Kk)];
  }
  for (int m = tid; m < Kk*6; m += 256) {  // assemble half-logits
    int k = m / 6, th = m % 6, t = th >> 1, h = th & 1;
    int o = k / NACT, a = k % NACT;
    int po = ((const int*)ws)[WS_PRED + b*MO + o];
    float v = ws[WS_LINP + (b*MO + o)*6 + th] + ws[WS_EO + po*6 + th] + ws[WS_EA + a*6 + th];
    if (h == 0) v += b_tr[t];
    s_L[m] = v;
  }
  __syncthreads();
  if (tid == 0) {
    int c = 0;
    for (int k = 0; k < Kk; ++k) { s_C[k] = c; c += s_sel[k]; }
    s_T = c;
  }
  __syncthreads();

  int T = s_T, Vtot = T*(T-1);
  int q = slice*256 + tid;
  if (q < Pp) {
    float* plog = out + OUT_PLOG + (size_t)b*Pp*NTRS;
    float* ttgt = out + OUT_TTGT + (size_t)b*Pp*NTRS;
    int i = q / (Kk-1);
    int jj = q - i*(Kk-1);
    int j = jj + (jj >= i ? 1 : 0);
    int si = s_sel[i], sj = s_sel[j];
    // # valid pairs strictly before (i,j) in lex order  -> O(1) packed position
    int vb = s_C[i]*(T-1) + (si ? (s_C[j] - (i < j ? 1 : 0)) : 0);
    bool valid = si && sj;
    int pos = valid ? vb : (Vtot + q - vb);
    float l0, l1, l2;
    if (valid) {
      l0 = s_L[i*6+0] + s_L[j*6+1];
      l1 = s_L[i*6+2] + s_L[j*6+3];
      l2 = s_L[i*6+4] + s_L[j*6+5];
    } else { l0 = s_inv[0]; l1 = s_inv[1]; l2 = s_inv[2]; }
    int ob = pos*3;
    plog[ob+0] = l0; plog[ob+1] = l1; plog[ob+2] = l2;
    if (valid) {
      const float* tr = TRt + (((size_t)b*Kk + i)*Kk + j)*NTRS;
      ttgt[ob+0] = tr[0]; ttgt[ob+1] = tr[1]; ttgt[ob+2] = tr[2];
      int base = (s_aa[i]*NAA + s_aa[j])*NTRS;
      unsigned* seg = (unsigned*)ws + WS_SEG + b*NCLS;
      atomicMax(&seg[aalut[base+0]], fmap(l0));
      atomicMax(&seg[aalut[base+1]], fmap(l1));
      atomicMax(&seg[aalut[base+2]], fmap(l2));
    } else {
      ttgt[ob+0] = -1.f; ttgt[ob+1] = -1.f; ttgt[ob+2] = -1.f;
    }
  }
}

// ---------------- K3: final merge ----------------
__global__ __launch_bounds__(320) void k3(float* __restrict__ out,
                                          const float* __restrict__ ws)
{
  int b = blockIdx.x, c = threadIdx.x;
  if (c < NCLS) {
    unsigned u = ((const unsigned*)ws)[WS_SEG + b*NCLS + c];
    out[OUT_FINAL + b*NCLS + c] = u ? funmap(u) : ws[WS_NE + b*NCLS + c];
  }
}

extern "C" void kernel_launch(void* const* d_in, const int* in_sizes, int n_in,
                              void* d_out, int out_size, void* d_ws, size_t ws_size,
                              hipStream_t stream) {
  (void)in_sizes; (void)n_in; (void)ws_size; (void)out_size;
  const float* inp      = (const float*)d_in[0];
  const float* objmask  = (const float*)d_in[1];
  const float* TRt      = (const float*)d_in[2];
  const float* W_obj    = (const float*)d_in[3];
  const float* b_obj    = (const float*)d_in[4];
  const float* W_act    = (const float*)d_in[5];
  const float* b_act    = (const float*)d_in[6];
  const float* W_tr     = (const float*)d_in[7];
  const float* b_tr     = (const float*)d_in[8];
  const float* W_ne     = (const float*)d_in[9];
  const float* b_ne     = (const float*)d_in[10];
  const float* obj_emb  = (const float*)d_in[11];
  const float* act_emb  = (const float*)d_in[12];
  const int*   AA       = (const int*)d_in[13];
  // d_in[14] = obj_act_lookup (eval-only)
  const int*   aalut    = (const int*)d_in[15];
  float* out = (float*)d_out;
  float* ws  = (float*)d_ws;

  hipLaunchKernelGGL(k1, dim3((W_TOT + 3) / 4), dim3(256), 0, stream,
                     inp, objmask, W_obj, b_obj, W_act, b_act, W_tr, b_tr,
                     W_ne, b_ne, obj_emb, act_emb, AA, out, ws);
  hipLaunchKernelGGL(k2, dim3(Bn * NSLICE), dim3(256), 0, stream,
                     TRt, b_tr, aalut, out, ws);
  hipLaunchKernelGGL(k3, dim3(Bn), dim3(320), 0, stream, out, ws);
}